// Round 19
// baseline (426.054 us; speedup 1.0000x reference)
//
#include <hip/hip_runtime.h>
#include <cstdint>
#include <cstddef>

// ---------------- constants ----------------
static const int B_ = 32, N_ = 512, C_ = 1024, C2_ = 1026, CC2_ = 2052;
static const int S0_ = 256, S1_ = 64, K_ = 16, OUT_ = 3584;
static const int LDP_ = 1152;   // padded row stride (multiple of 128 and 64)
static const int KEFF_ = 1088;  // 17*64 >= C2_; cols [1026,1088) are zeros -> bit-identical

typedef unsigned short ushort;
typedef __attribute__((ext_vector_type(8))) short short8;
typedef __attribute__((ext_vector_type(4))) float f32x4;

__device__ __forceinline__ ushort f2bf(float x) {
  unsigned u = __float_as_uint(x);
  unsigned r = (u + 0x7fffu + ((u >> 16) & 1u)) >> 16;
  return (ushort)r;
}
__device__ __forceinline__ float bf2f(ushort b) {
  return __uint_as_float(((unsigned)b) << 16);
}

__device__ __forceinline__ void gload16(const void* g, void* l) {
  __builtin_amdgcn_global_load_lds((const __attribute__((address_space(1))) void*)g,
                                   (__attribute__((address_space(3))) void*)l, 16, 0, 0);
}

// ---- DS-free wave-64 unsigned-max reduce via DPP; result valid in lane 63 ----
__device__ __forceinline__ unsigned wave_umax_dpp(unsigned v) {
  unsigned t;
  t = (unsigned)__builtin_amdgcn_update_dpp(0, (int)v, 0x111, 0xf, 0xf, true);  // row_shr:1
  v = v > t ? v : t;
  t = (unsigned)__builtin_amdgcn_update_dpp(0, (int)v, 0x112, 0xf, 0xf, true);  // row_shr:2
  v = v > t ? v : t;
  t = (unsigned)__builtin_amdgcn_update_dpp(0, (int)v, 0x114, 0xf, 0xf, true);  // row_shr:4
  v = v > t ? v : t;
  t = (unsigned)__builtin_amdgcn_update_dpp(0, (int)v, 0x118, 0xf, 0xf, true);  // row_shr:8
  v = v > t ? v : t;
  t = (unsigned)__builtin_amdgcn_update_dpp(0, (int)v, 0x142, 0xf, 0xf, true);  // row_bcast15
  v = v > t ? v : t;
  t = (unsigned)__builtin_amdgcn_update_dpp(0, (int)v, 0x143, 0xf, 0xf, true);  // row_bcast31
  v = v > t ? v : t;
  return v;
}

// ================= device GEMM (128x128 tile, 4 waves, 16x16x32 MFMA, BK=64 two-half) ========
// OMODE 1: bf16 out, zero for c>=Neff. OMODE 2: bf16 out + f32 bias.
template <int OMODE>
__device__ __forceinline__ void dev_mgemm(int bx, int by, ushort* As, ushort* Bs, int M, int Neff,
                                          int K, const ushort* __restrict__ A, int lda,
                                          const int* __restrict__ rowidx,
                                          const ushort* __restrict__ Wt, int ldw,
                                          const float* __restrict__ bias,
                                          void* __restrict__ Cout, int ldc) {
  int t = threadIdx.x;
  int w = t >> 6, l = t & 63;
  int row0 = by * 128, col0 = bx * 128;
  f32x4 acc[4][4];
#pragma unroll
  for (int i = 0; i < 4; i++)
#pragma unroll
    for (int j = 0; j < 4; j++) acc[i][j] = (f32x4){0.f, 0.f, 0.f, 0.f};

  int srow = l >> 2;       // 0..15
  int scol = (l & 3) * 8;  // 0,8,16,24
  int ar0 = min(row0 + w * 16 + srow, M - 1);
  int ar1 = min(row0 + 64 + w * 16 + srow, M - 1);
  if (rowidx) { ar0 = rowidx[ar0]; ar1 = rowidx[ar1]; }
  const ushort* gA0 = A + (size_t)ar0 * lda + scol;
  const ushort* gA1 = A + (size_t)ar1 * lda + scol;
  const ushort* gB0 = Wt + (size_t)(col0 + w * 16 + srow) * ldw + scol;
  const ushort* gB1 = Wt + (size_t)(col0 + 64 + w * 16 + srow) * ldw + scol;
  ushort* lA0 = As + w * 512;
  ushort* lA1 = As + 2048 + w * 512;
  ushort* lB0 = Bs + w * 512;
  ushort* lB1 = Bs + 2048 + w * 512;

  int wm = w >> 1, wn = w & 1;
  int fr = l & 15, fg = l >> 4;

  for (int kt = 0; kt < K; kt += 64) {
    __syncthreads();
    gload16(gA0 + kt, lA0);
    gload16(gA1 + kt, lA1);
    gload16(gB0 + kt, lB0);
    gload16(gB1 + kt, lB1);
    gload16(gA0 + kt + 32, lA0 + 4096);
    gload16(gA1 + kt + 32, lA1 + 4096);
    gload16(gB0 + kt + 32, lB0 + 4096);
    gload16(gB1 + kt + 32, lB1 + 4096);
    __syncthreads();
#pragma unroll
    for (int ks = 0; ks < 2; ks++) {
      short8 af[4], bf[4];
#pragma unroll
      for (int mi = 0; mi < 4; mi++)
        af[mi] = *(const short8*)&As[ks * 4096 + (wm * 64 + mi * 16 + fr) * 32 + fg * 8];
#pragma unroll
      for (int ni = 0; ni < 4; ni++)
        bf[ni] = *(const short8*)&Bs[ks * 4096 + (wn * 64 + ni * 16 + fr) * 32 + fg * 8];
#pragma unroll
      for (int mi = 0; mi < 4; mi++)
#pragma unroll
        for (int ni = 0; ni < 4; ni++)
          acc[mi][ni] =
              __builtin_amdgcn_mfma_f32_16x16x32_bf16(af[mi], bf[ni], acc[mi][ni], 0, 0, 0);
    }
  }

  ushort* C = (ushort*)Cout;
  if (OMODE == 1) {
#pragma unroll
    for (int mi = 0; mi < 4; mi++)
#pragma unroll
      for (int ni = 0; ni < 4; ni++)
#pragma unroll
        for (int q = 0; q < 4; q++) {
          int r = row0 + wm * 64 + mi * 16 + fg * 4 + q;
          int c = col0 + wn * 64 + ni * 16 + fr;
          if (r < M) C[(size_t)r * ldc + c] = f2bf(c < Neff ? acc[mi][ni][q] : 0.f);
        }
  } else {
#pragma unroll
    for (int mi = 0; mi < 4; mi++)
#pragma unroll
      for (int ni = 0; ni < 4; ni++)
#pragma unroll
        for (int q = 0; q < 4; q++) {
          int r = row0 + wm * 64 + mi * 16 + fg * 4 + q;
          int c = col0 + wn * 64 + ni * 16 + fr;
          if (r < M) C[(size_t)r * ldc + c] = f2bf(acc[mi][ni][q] + bias[c]);
        }
  }
}

// ================= device GEMM BIG (256x128 tile, 8 waves / 512 threads, BK=64 two-half) =====
// A staged twice, B once per half -> 25% less staging per MFMA; (kt,ks) order identical to
// dev_mgemm -> bit-identical accumulation. As: 16384 ushorts, Bs: 8192 ushorts (48KB LDS).
template <int OMODE>
__device__ __forceinline__ void dev_mgemm_big(int bx, int by, ushort* As, ushort* Bs, int M,
                                              int Neff, int K, const ushort* __restrict__ A,
                                              int lda, const int* __restrict__ rowidx,
                                              const ushort* __restrict__ Wt, int ldw,
                                              const float* __restrict__ bias,
                                              void* __restrict__ Cout, int ldc) {
  int t = threadIdx.x;
  int w = t >> 6, l = t & 63;
  int row0 = by * 256, col0 = bx * 128;
  f32x4 acc[4][4];
#pragma unroll
  for (int i = 0; i < 4; i++)
#pragma unroll
    for (int j = 0; j < 4; j++) acc[i][j] = (f32x4){0.f, 0.f, 0.f, 0.f};

  int srow = l >> 2;       // 0..15
  int scol = (l & 3) * 8;  // 0,8,16,24
  int ar0 = min(row0 + w * 16 + srow, M - 1);        // rows 0..127
  int ar1 = min(row0 + 128 + w * 16 + srow, M - 1);  // rows 128..255
  if (rowidx) { ar0 = rowidx[ar0]; ar1 = rowidx[ar1]; }
  const ushort* gA0 = A + (size_t)ar0 * lda + scol;
  const ushort* gA1 = A + (size_t)ar1 * lda + scol;
  const ushort* gB0 = Wt + (size_t)(col0 + w * 16 + srow) * ldw + scol;  // 8 waves = 128 rows
  ushort* lA0 = As + w * 512;         // rows 0..127 of half
  ushort* lA1 = As + 4096 + w * 512;  // rows 128..255 of half
  ushort* lB0 = Bs + w * 512;         // all 128 B rows

  int wm = w >> 1, wn = w & 1;  // wm 0..3 (64-row slab), wn 0..1 (64-col slab)
  int fr = l & 15, fg = l >> 4;

  for (int kt = 0; kt < K; kt += 64) {
    __syncthreads();
    gload16(gA0 + kt, lA0);
    gload16(gA1 + kt, lA1);
    gload16(gB0 + kt, lB0);
    gload16(gA0 + kt + 32, lA0 + 8192);
    gload16(gA1 + kt + 32, lA1 + 8192);
    gload16(gB0 + kt + 32, lB0 + 4096);
    __syncthreads();
#pragma unroll
    for (int ks = 0; ks < 2; ks++) {
      short8 af[4], bf[4];
#pragma unroll
      for (int mi = 0; mi < 4; mi++)
        af[mi] = *(const short8*)&As[ks * 8192 + (wm * 64 + mi * 16 + fr) * 32 + fg * 8];
#pragma unroll
      for (int ni = 0; ni < 4; ni++)
        bf[ni] = *(const short8*)&Bs[ks * 4096 + (wn * 64 + ni * 16 + fr) * 32 + fg * 8];
#pragma unroll
      for (int mi = 0; mi < 4; mi++)
#pragma unroll
        for (int ni = 0; ni < 4; ni++)
          acc[mi][ni] =
              __builtin_amdgcn_mfma_f32_16x16x32_bf16(af[mi], bf[ni], acc[mi][ni], 0, 0, 0);
    }
  }

  ushort* C = (ushort*)Cout;
  if (OMODE == 1) {
#pragma unroll
    for (int mi = 0; mi < 4; mi++)
#pragma unroll
      for (int ni = 0; ni < 4; ni++)
#pragma unroll
        for (int q = 0; q < 4; q++) {
          int r = row0 + wm * 64 + mi * 16 + fg * 4 + q;
          int c = col0 + wn * 64 + ni * 16 + fr;
          if (r < M) C[(size_t)r * ldc + c] = f2bf(c < Neff ? acc[mi][ni][q] : 0.f);
        }
  } else {
#pragma unroll
    for (int mi = 0; mi < 4; mi++)
#pragma unroll
      for (int ni = 0; ni < 4; ni++)
#pragma unroll
        for (int q = 0; q < 4; q++) {
          int r = row0 + wm * 64 + mi * 16 + fg * 4 + q;
          int c = col0 + wn * 64 + ni * 16 + fr;
          if (r < M) C[(size_t)r * ldc + c] = f2bf(acc[mi][ni][q] + bias[c]);
        }
  }
}

// ================= device FPS: DS-free (DPP reduce + readlane broadcast), prio 3 =============
template <int NPL>
__device__ __forceinline__ void dev_fps(int b, int Np, int nsub, const float* __restrict__ pts,
                                        int stride, int* __restrict__ rows) {
  __builtin_amdgcn_s_setprio(3);
  int lane = threadIdx.x;  // caller guarantees < 64
  const float* pb = pts + (size_t)b * Np * stride;
  float px[NPL], py[NPL], dist[NPL];
#pragma unroll
  for (int i = 0; i < NPL; i++) {
    int j = lane + 64 * i;
    px[i] = pb[(size_t)j * stride + 0];
    py[i] = pb[(size_t)j * stride + 1];
    dist[i] = 1e10f;
  }
  int far = 0;
  float fx = pb[0], fy = pb[1];
  for (int s = 0; s < nsub; s++) {
    if (lane == 0) rows[b * nsub + s] = b * Np + far;
    unsigned bd = 0;
    int bidx = lane;
#pragma unroll
    for (int i = 0; i < NPL; i++) {
      float dx = __fsub_rn(px[i], fx), dy = __fsub_rn(py[i], fy);
      float d = __fadd_rn(__fmul_rn(dx, dx), __fmul_rn(dy, dy));
      dist[i] = fminf(dist[i], d);
      unsigned db = __float_as_uint(dist[i]);
      if (i == 0) {
        bd = db;
      } else if (db > bd) {
        bd = db;
        bidx = lane + 64 * i;
      }
    }
    unsigned maxd = (unsigned)__builtin_amdgcn_readlane((int)wave_umax_dpp(bd), 63);
    unsigned cand = (bd == maxd) ? ~(unsigned)bidx : 0u;
    far = (int)~(unsigned)__builtin_amdgcn_readlane((int)wave_umax_dpp(cand), 63);
    int chunk = far >> 6, owner = far & 63;
    float cx = px[0], cy = py[0];
#pragma unroll
    for (int i = 1; i < NPL; i++) {
      bool cnd = (chunk == i);
      cx = cnd ? px[i] : cx;
      cy = cnd ? py[i] : cy;
    }
    fx = __uint_as_float((unsigned)__builtin_amdgcn_readlane((int)__float_as_uint(cx), owner));
    fy = __uint_as_float((unsigned)__builtin_amdgcn_readlane((int)__float_as_uint(cy), owner));
  }
  __builtin_amdgcn_s_setprio(0);
}

// ================= device kNN: DS-free (DPP min via complemented max) =======================
template <int NPL>
__device__ __forceinline__ void dev_knn(int bs, int S, int Np, const float* __restrict__ pts,
                                        int stride, const int* __restrict__ rows,
                                        int* __restrict__ nn) {
  int b = bs / S;
  int lane = threadIdx.x & 63;
  const float* pb = pts + (size_t)b * Np * stride;
  int arow = rows[bs];
  float ax = pts[(size_t)arow * stride + 0];
  float ay = pts[(size_t)arow * stride + 1];
  unsigned d2[NPL];
#pragma unroll
  for (int i = 0; i < NPL; i++) {
    int j = lane + 64 * i;
    float dx = __fsub_rn(ax, pb[(size_t)j * stride + 0]);
    float dy = __fsub_rn(ay, pb[(size_t)j * stride + 1]);
    d2[i] = __float_as_uint(__fadd_rn(__fmul_rn(dx, dx), __fmul_rn(dy, dy)));
  }
  unsigned mask = 0;
  for (int k = 0; k < K_; k++) {
    unsigned bd = 0xFFFFFFFFu;
    int bidx = 0x7fffffff;
#pragma unroll
    for (int i = 0; i < NPL; i++) {
      int j = lane + 64 * i;
      bool used = (mask >> i) & 1u;
      if (!used && (d2[i] < bd || (d2[i] == bd && j < bidx))) { bd = d2[i]; bidx = j; }
    }
    unsigned mind = ~(unsigned)__builtin_amdgcn_readlane((int)wave_umax_dpp(~bd), 63);
    unsigned cand = (bd == mind) ? ~(unsigned)bidx : 0u;
    int bi = (int)~(unsigned)__builtin_amdgcn_readlane((int)wave_umax_dpp(cand), 63);
    if ((bi & 63) == lane) mask |= 1u << (bi >> 6);
    if (lane == 0) nn[bs * K_ + k] = b * Np + bi;
  }
}

// ================= device bilinear ===========================================================
__device__ __forceinline__ void dev_bilinear(int r, const float* __restrict__ points,
                                             const float* __restrict__ fmT,
                                             ushort* __restrict__ X0) {
  float p0 = points[r * 2 + 0], p1 = points[r * 2 + 1];
  float g0 = __fsub_rn(__fmul_rn(2.0f, p1), 1.0f);
  float g1 = __fsub_rn(__fmul_rn(2.0f, p0), 1.0f);
  float x = __fmul_rn(__fmul_rn(__fadd_rn(g0, 1.0f), 0.5f), 31.0f);
  float y = __fmul_rn(__fmul_rn(__fadd_rn(g1, 1.0f), 0.5f), 31.0f);
  float x0f = floorf(x), y0f = floorf(y);
  float wx = __fsub_rn(x, x0f), wy = __fsub_rn(y, y0f);
  int x0i = (int)fminf(fmaxf(x0f, 0.f), 31.f);
  int x1i = (int)fminf(fmaxf(__fadd_rn(x0f, 1.f), 0.f), 31.f);
  int y0i = (int)fminf(fmaxf(y0f, 0.f), 31.f);
  int y1i = (int)fminf(fmaxf(__fadd_rn(y0f, 1.f), 0.f), 31.f);
  float omwx = __fsub_rn(1.f, wx), omwy = __fsub_rn(1.f, wy);
  size_t i00 = (size_t)(y0i * 32 + x0i) * 1024;
  size_t i01 = (size_t)(y0i * 32 + x1i) * 1024;
  size_t i10 = (size_t)(y1i * 32 + x0i) * 1024;
  size_t i11 = (size_t)(y1i * 32 + x1i) * 1024;
  int t = threadIdx.x;
  int c0 = t * 4;
  ushort* xr = X0 + (size_t)r * LDP_;
  float4 f00 = *(const float4*)(fmT + i00 + c0);
  float4 f01 = *(const float4*)(fmT + i01 + c0);
  float4 f10 = *(const float4*)(fmT + i10 + c0);
  float4 f11 = *(const float4*)(fmT + i11 + c0);
  float a[4] = {f00.x, f00.y, f00.z, f00.w};
  float b[4] = {f01.x, f01.y, f01.z, f01.w};
  float c[4] = {f10.x, f10.y, f10.z, f10.w};
  float d[4] = {f11.x, f11.y, f11.z, f11.w};
  ushort o[4];
#pragma unroll
  for (int i = 0; i < 4; i++) {
    float t1 = a[i] * omwx * omwy;
    float t2 = b[i] * wx * omwy;
    float t3 = c[i] * omwx * wy;
    float t4 = d[i] * wx * wy;
    o[i] = f2bf(((t1 + t2) + t3) + t4);
  }
  uint2 uv = {(unsigned)o[0] | ((unsigned)o[1] << 16), (unsigned)o[2] | ((unsigned)o[3] << 16)};
  *(uint2*)(xr + c0) = uv;
  if (t == 0) { xr[1024] = f2bf(p0); xr[1025] = f2bf(p1); }
  if (t < 126) xr[1026 + t] = 0;
}

// ================= merged weight prep: aw cvts + dw transposes + dvec + fm transpose =========
static const int PREP_CVT = 2304;  // per aw job: 1024*1152/2/256
static const int PREP_TT = 1296;   // 36x36 tiles
static const int PREP_FMT = 1024;  // 32x32 tiles of feat_map
static const int PREP_TOTAL = 4 * PREP_CVT + 2 * PREP_TT + 512 + PREP_FMT;

__global__ __launch_bounds__(256) void k_prep(
    const float* __restrict__ aw0, const float* __restrict__ aw1, const float* __restrict__ dw0,
    const float* __restrict__ dw1, const float* __restrict__ db0, const float* __restrict__ ab0,
    const float* __restrict__ db1, const float* __restrict__ ab1,
    const float* __restrict__ feat_map, ushort* __restrict__ awdb0, ushort* __restrict__ awab0,
    ushort* __restrict__ awdb1, ushort* __restrict__ awab1, ushort* __restrict__ dwT0,
    ushort* __restrict__ dwT1, float* __restrict__ dvp0, float* __restrict__ dvp1,
    float* __restrict__ fmT) {
  __shared__ float tile[32][33];
  int bid = blockIdx.x;
  if (bid < 4 * PREP_CVT) {
    int job = bid / PREP_CVT, lb = bid % PREP_CVT;
    const float* src = (job < 2) ? aw0 : aw1;
    int soff = (job & 1) ? C2_ : 0;
    ushort* dst = (job == 0) ? awdb0 : (job == 1) ? awab0 : (job == 2) ? awdb1 : awab1;
    unsigned e = (lb * 256u + threadIdx.x) * 2u;
    unsigned r = e / (unsigned)LDP_, c = e % (unsigned)LDP_;
    float v0 = 0.f, v1 = 0.f;
    const float* sp = src + (size_t)r * CC2_ + soff + c;
    if ((int)c < C2_) v0 = sp[0];
    if ((int)(c + 1) < C2_) v1 = sp[1];
    *(unsigned*)(dst + e) = (unsigned)f2bf(v0) | ((unsigned)f2bf(v1) << 16);
    return;
  }
  bid -= 4 * PREP_CVT;
  if (bid < 2 * PREP_TT) {
    int which = bid / PREP_TT, id = bid % PREP_TT;
    const float* src = which ? dw1 : dw0;
    ushort* dst = which ? dwT1 : dwT0;
    int bx = (id % 36) * 32, by = (id / 36) * 32;
    int tx = threadIdx.x & 31, ty4 = (threadIdx.x >> 5) * 4;
#pragma unroll
    for (int i = 0; i < 4; i++) {
      int r = by + ty4 + i, c = bx + tx;
      tile[ty4 + i][tx] = (r < C2_ && c < C2_) ? src[(size_t)r * C2_ + c] : 0.f;
    }
    __syncthreads();
#pragma unroll
    for (int i = 0; i < 4; i++)
      dst[(size_t)(bx + ty4 + i) * LDP_ + by + tx] = f2bf(tile[tx][ty4 + i]);
    return;
  }
  bid -= 2 * PREP_TT;
  if (bid < 512) {
    int which = bid >> 8;
    int cb = bid & 255;
    const float* aw = which ? aw1 : aw0;
    const float* db = which ? db1 : db0;
    const float* ab = which ? ab1 : ab0;
    float* dvp = which ? dvp1 : dvp0;
    int w = threadIdx.x >> 6, lane = threadIdx.x & 63;
    int c = cb * 4 + w;
    const float* wr = aw + (size_t)c * CC2_;
    float s = 0.f;
    for (int d = lane; d < C2_; d += 64) s += db[d] * wr[d];
#pragma unroll
    for (int off = 32; off; off >>= 1) s += __shfl_xor(s, off);
    if (lane == 0) dvp[c] = ab[c] + s;
    return;
  }
  bid -= 512;
  {
    int yx0 = (bid & 31) * 32, c0 = (bid >> 5) * 32;
    int tx = threadIdx.x & 31, ty = threadIdx.x >> 5;
#pragma unroll
    for (int i = 0; i < 4; i++)
      tile[ty + 8 * i][tx] = feat_map[(size_t)(c0 + ty + 8 * i) * 1024 + yx0 + tx];
    __syncthreads();
#pragma unroll
    for (int i = 0; i < 4; i++)
      fmT[(size_t)(yx0 + ty + 8 * i) * 1024 + c0 + tx] = tile[tx][ty + 8 * i];
  }
}

// ================= merged: FPS0 (prio 3, DS-free) + Wc combine GEMMs + bilinear =============
__global__ __launch_bounds__(256) void k_wc_bil(
    const ushort* __restrict__ awdb0, const ushort* __restrict__ dwT0, ushort* __restrict__ Wcb0,
    const ushort* __restrict__ awdb1, const ushort* __restrict__ dwT1, ushort* __restrict__ Wcb1,
    const float* __restrict__ points, const float* __restrict__ fmT, ushort* __restrict__ Xb0,
    int* __restrict__ rows0) {
  __shared__ ushort As[8192];
  __shared__ ushort Bs[8192];
  int bid = blockIdx.x;
  if (bid < 32) {
    if (threadIdx.x < 64) dev_fps<8>(bid, N_, S0_, points, 2, rows0);
    return;
  }
  bid -= 32;
  if (bid < 72) {
    dev_mgemm<1>(bid / 8, bid % 8, As, Bs, C_, C2_, KEFF_, awdb0, LDP_, nullptr, dwT0, LDP_,
                 nullptr, Wcb0, LDP_);
  } else if (bid < 144) {
    int b2 = bid - 72;
    dev_mgemm<1>(b2 / 8, b2 % 8, As, Bs, C_, C2_, KEFF_, awdb1, LDP_, nullptr, dwT1, LDP_, nullptr,
                 Wcb1, LDP_);
  } else {
    dev_bilinear(bid - 144, points, fmT, Xb0);
  }
}

// ================= merged stage 0 (512 threads): G0 big + P0 big + kNN0 =====================
// blocks: [0,512) G0 (nrb=64) | [512,768) P0 (nrb=32) | [768,1792) kNN0 (8 q/block = 8192)
__global__ __launch_bounds__(512) void k_stage0(
    const ushort* __restrict__ Xb0, const ushort* __restrict__ Wcb0, ushort* __restrict__ Gb,
    const int* __restrict__ rows0, const ushort* __restrict__ awab0,
    const float* __restrict__ dvp0, ushort* __restrict__ Pb, const float* __restrict__ points,
    int* __restrict__ nn0) {
  __shared__ ushort As[16384];
  __shared__ ushort Bs[8192];
  int bid = blockIdx.x;
  if (bid < 512) {
    dev_mgemm_big<1>(bid / 64, bid % 64, As, Bs, B_ * N_, C_, KEFF_, Xb0, LDP_, nullptr, Wcb0,
                     LDP_, nullptr, Gb, C_);
    return;
  }
  if (bid < 768) {
    int b2 = bid - 512;
    dev_mgemm_big<2>(b2 / 32, b2 % 32, As, Bs, B_ * S0_, C_, KEFF_, Xb0, LDP_, rows0, awab0, LDP_,
                     dvp0, Pb, C_);
    return;
  }
  int w = threadIdx.x >> 6;
  int qid = (bid - 768) * 8 + w;  // 1024 blocks x 8 waves = 8192 queries
  dev_knn<8>(qid, S0_, N_, points, 2, rows0, nn0);
}

// ================= merged stage 1 (512 threads): FPS1 + G1 big ==============================
// blocks: [0,32) FPS1 | [32,288) G1 (nrb=32)
__global__ __launch_bounds__(512) void k_gemm_fps1(const ushort* __restrict__ Xb1,
                                                   const ushort* __restrict__ Wcb1,
                                                   ushort* __restrict__ Gout,
                                                   const float* __restrict__ coords1,
                                                   int* __restrict__ rows1) {
  __shared__ ushort As[16384];
  __shared__ ushort Bs[8192];
  int bid = blockIdx.x;
  if (bid < 32) {
    if (threadIdx.x < 64) dev_fps<4>(bid, S0_, S1_, coords1, 2, rows1);
    return;
  }
  int b2 = bid - 32;
  dev_mgemm_big<1>(b2 / 32, b2 % 32, As, Bs, B_ * S0_, C_, KEFF_, Xb1, LDP_, nullptr, Wcb1, LDP_,
                   nullptr, Gout, C_);
}

// ================= merged stage 1b (512 threads): P1 big + kNN1 =============================
// blocks: [0,64) P1 (nrb=8: 8 row-tiles x 8 col-tiles) | [64,320) kNN1 (8 q/block = 2048)
__global__ __launch_bounds__(512) void k_p1_knn1(const ushort* __restrict__ Xb1,
                                                 const int* __restrict__ rows1,
                                                 const ushort* __restrict__ awab1,
                                                 const float* __restrict__ dvp1,
                                                 ushort* __restrict__ Pb,
                                                 const float* __restrict__ coords1,
                                                 int* __restrict__ nn1) {
  __shared__ ushort As[16384];
  __shared__ ushort Bs[8192];
  int bid = blockIdx.x;
  if (bid < 64) {
    dev_mgemm_big<2>(bid / 8, bid % 8, As, Bs, B_ * S1_, C_, KEFF_, Xb1, LDP_, rows1, awab1, LDP_,
                     dvp1, Pb, C_);
    return;
  }
  int w = threadIdx.x >> 6;
  int qid = (bid - 64) * 8 + w;  // 256 blocks x 8 waves = 2048 queries
  dev_knn<4>(qid, S1_, S0_, coords1, 2, rows1, nn1);
}

// ================= flat head GEMM with fused f32->bf16 W conversion =========================
__global__ __launch_bounds__(256) void k_flat(const ushort* __restrict__ A,  // [32][65536] bf16
                                              const float* __restrict__ W,   // [1024][65536] f32
                                              float* __restrict__ Cp) {      // [32][32][1024]
  int t = threadIdx.x;
  int w = t >> 6, l = t & 63;
  int fr = l & 15, fg = l >> 4;
  int col0 = blockIdx.x * 128 + w * 32;
  size_t k0 = (size_t)blockIdx.z * 2048;
  f32x4 acc[2][2];
#pragma unroll
  for (int i = 0; i < 2; i++)
#pragma unroll
    for (int j = 0; j < 2; j++) acc[i][j] = (f32x4){0.f, 0.f, 0.f, 0.f};
  const ushort* a0 = A + (size_t)fr * 65536 + k0 + fg * 8;
  const ushort* a1 = A + (size_t)(16 + fr) * 65536 + k0 + fg * 8;
  const float* b0 = W + (size_t)(col0 + fr) * 65536 + k0 + fg * 8;
  const float* b1 = W + (size_t)(col0 + 16 + fr) * 65536 + k0 + fg * 8;
  for (int kt = 0; kt < 2048; kt += 32) {
    short8 af0 = *(const short8*)(a0 + kt);
    short8 af1 = *(const short8*)(a1 + kt);
    float4 p0 = *(const float4*)(b0 + kt);
    float4 p1 = *(const float4*)(b0 + kt + 4);
    float4 q0 = *(const float4*)(b1 + kt);
    float4 q1 = *(const float4*)(b1 + kt + 4);
    short8 bf0, bf1;
    bf0[0] = (short)f2bf(p0.x); bf0[1] = (short)f2bf(p0.y);
    bf0[2] = (short)f2bf(p0.z); bf0[3] = (short)f2bf(p0.w);
    bf0[4] = (short)f2bf(p1.x); bf0[5] = (short)f2bf(p1.y);
    bf0[6] = (short)f2bf(p1.z); bf0[7] = (short)f2bf(p1.w);
    bf1[0] = (short)f2bf(q0.x); bf1[1] = (short)f2bf(q0.y);
    bf1[2] = (short)f2bf(q0.z); bf1[3] = (short)f2bf(q0.w);
    bf1[4] = (short)f2bf(q1.x); bf1[5] = (short)f2bf(q1.y);
    bf1[6] = (short)f2bf(q1.z); bf1[7] = (short)f2bf(q1.w);
    acc[0][0] = __builtin_amdgcn_mfma_f32_16x16x32_bf16(af0, bf0, acc[0][0], 0, 0, 0);
    acc[1][0] = __builtin_amdgcn_mfma_f32_16x16x32_bf16(af1, bf0, acc[1][0], 0, 0, 0);
    acc[0][1] = __builtin_amdgcn_mfma_f32_16x16x32_bf16(af0, bf1, acc[0][1], 0, 0, 0);
    acc[1][1] = __builtin_amdgcn_mfma_f32_16x16x32_bf16(af1, bf1, acc[1][1], 0, 0, 0);
  }
  float* Cz = Cp + (size_t)blockIdx.z * 32 * 1024;
#pragma unroll
  for (int mi = 0; mi < 2; mi++)
#pragma unroll
    for (int ni = 0; ni < 2; ni++)
#pragma unroll
      for (int q = 0; q < 4; q++) {
        int r = mi * 16 + fg * 4 + q;
        int c = col0 + ni * 16 + fr;
        Cz[(size_t)r * 1024 + c] = acc[mi][ni][q];
      }
}

// ================= dim head GEMM (z-split 4 x 256) with fused f32->bf16 W conversion ========
__global__ __launch_bounds__(256) void k_dim(const ushort* __restrict__ A,
                                             const float* __restrict__ W,
                                             float* __restrict__ Cp) {
  int t = threadIdx.x;
  int w = t >> 6, l = t & 63;
  int fr = l & 15, fg = l >> 4;
  int col0 = blockIdx.x * 128 + w * 32;
  int k0 = blockIdx.z * 256;
  f32x4 acc[2][2];
#pragma unroll
  for (int i = 0; i < 2; i++)
#pragma unroll
    for (int j = 0; j < 2; j++) acc[i][j] = (f32x4){0.f, 0.f, 0.f, 0.f};
  const ushort* a0 = A + (size_t)fr * 1024 + k0 + fg * 8;
  const ushort* a1 = A + (size_t)(16 + fr) * 1024 + k0 + fg * 8;
  const float* b0 = W + (size_t)(col0 + fr) * 1024 + k0 + fg * 8;
  const float* b1 = W + (size_t)(col0 + 16 + fr) * 1024 + k0 + fg * 8;
  for (int kt = 0; kt < 256; kt += 32) {
    short8 af0 = *(const short8*)(a0 + kt);
    short8 af1 = *(const short8*)(a1 + kt);
    float4 p0 = *(const float4*)(b0 + kt);
    float4 p1 = *(const float4*)(b0 + kt + 4);
    float4 q0 = *(const float4*)(b1 + kt);
    float4 q1 = *(const float4*)(b1 + kt + 4);
    short8 bf0, bf1;
    bf0[0] = (short)f2bf(p0.x); bf0[1] = (short)f2bf(p0.y);
    bf0[2] = (short)f2bf(p0.z); bf0[3] = (short)f2bf(p0.w);
    bf0[4] = (short)f2bf(p1.x); bf0[5] = (short)f2bf(p1.y);
    bf0[6] = (short)f2bf(p1.z); bf0[7] = (short)f2bf(p1.w);
    bf1[0] = (short)f2bf(q0.x); bf1[1] = (short)f2bf(q0.y);
    bf1[2] = (short)f2bf(q0.z); bf1[3] = (short)f2bf(q0.w);
    bf1[4] = (short)f2bf(q1.x); bf1[5] = (short)f2bf(q1.y);
    bf1[6] = (short)f2bf(q1.z); bf1[7] = (short)f2bf(q1.w);
    acc[0][0] = __builtin_amdgcn_mfma_f32_16x16x32_bf16(af0, bf0, acc[0][0], 0, 0, 0);
    acc[1][0] = __builtin_amdgcn_mfma_f32_16x16x32_bf16(af1, bf0, acc[1][0], 0, 0, 0);
    acc[0][1] = __builtin_amdgcn_mfma_f32_16x16x32_bf16(af0, bf1, acc[0][1], 0, 0, 0);
    acc[1][1] = __builtin_amdgcn_mfma_f32_16x16x32_bf16(af1, bf1, acc[1][1], 0, 0, 0);
  }
  float* Cz = Cp + (size_t)blockIdx.z * 32 * 3584;
#pragma unroll
  for (int mi = 0; mi < 2; mi++)
#pragma unroll
    for (int ni = 0; ni < 2; ni++)
#pragma unroll
      for (int q = 0; q < 4; q++) {
        int r = mi * 16 + fg * 4 + q;
        int c = col0 + ni * 16 + fr;
        Cz[(size_t)r * 3584 + c] = acc[mi][ni][q];
      }
}

// ================= fused stage: wave-per-k, barrier-free k-loop, XCD-chunked ================
__global__ __launch_bounds__(256) void k_fused_stage(
    const ushort* __restrict__ G, const ushort* __restrict__ Pb, const int* __restrict__ rows,
    const int* __restrict__ nn, const float* __restrict__ lng, const float* __restrict__ lnb,
    const float* __restrict__ prev_pts, int pts_stride, ushort* __restrict__ Xout, int ld_out,
    float* __restrict__ coords_out) {
  __shared__ float sm[4][1024];
  int chunk = (int)gridDim.x >> 3;
  int bs = (blockIdx.x & 7) * chunk + (blockIdx.x >> 3);
  int t = threadIdx.x;
  int w = t >> 6, lane = t & 63;
  int c0 = lane * 16;
  int arow = rows[bs];
  float base[16], lg[16], lb[16], acc[16];
  {
    short8 pA = *(const short8*)(Pb + (size_t)bs * C_ + c0);
    short8 pB = *(const short8*)(Pb + (size_t)bs * C_ + c0 + 8);
    short8 gA = *(const short8*)(G + (size_t)arow * C_ + c0);
    short8 gB = *(const short8*)(G + (size_t)arow * C_ + c0 + 8);
#pragma unroll
    for (int i = 0; i < 8; i++) {
      base[i] = bf2f((ushort)pA[i]) - bf2f((ushort)gA[i]);
      base[8 + i] = bf2f((ushort)pB[i]) - bf2f((ushort)gB[i]);
    }
#pragma unroll
    for (int i = 0; i < 4; i++) {
      float4 gv = *(const float4*)(lng + c0 + 4 * i);
      float4 bv = *(const float4*)(lnb + c0 + 4 * i);
      lg[4 * i] = gv.x; lg[4 * i + 1] = gv.y; lg[4 * i + 2] = gv.z; lg[4 * i + 3] = gv.w;
      lb[4 * i] = bv.x; lb[4 * i + 1] = bv.y; lb[4 * i + 2] = bv.z; lb[4 * i + 3] = bv.w;
      acc[4 * i] = -INFINITY; acc[4 * i + 1] = -INFINITY;
      acc[4 * i + 2] = -INFINITY; acc[4 * i + 3] = -INFINITY;
    }
  }
#pragma unroll
  for (int kk = 0; kk < 4; kk++) {
    int g = nn[bs * K_ + w * 4 + kk];
    const ushort* Gr = G + (size_t)g * C_ + c0;
    short8 xA = *(const short8*)(Gr);
    short8 xB = *(const short8*)(Gr + 8);
    float v[16];
    float s1 = 0.f, s2 = 0.f;
#pragma unroll
    for (int i = 0; i < 8; i++) {
      float x = fmaxf(bf2f((ushort)xA[i]) + base[i], 0.f);
      v[i] = x; s1 += x; s2 += x * x;
      float y = fmaxf(bf2f((ushort)xB[i]) + base[8 + i], 0.f);
      v[8 + i] = y; s1 += y; s2 += y * y;
    }
#pragma unroll
    for (int off = 32; off; off >>= 1) {
      s1 += __shfl_xor(s1, off);
      s2 += __shfl_xor(s2, off);
    }
    float mu = s1 * (1.f / 1024.f);
    float var = s2 * (1.f / 1024.f) - mu * mu;
    float rstd = 1.f / sqrtf(var + 1e-5f);
#pragma unroll
    for (int i = 0; i < 16; i++) {
      float nv = (v[i] - mu) * rstd * lg[i] + lb[i];
      acc[i] = fmaxf(acc[i], nv);
    }
  }
#pragma unroll
  for (int i = 0; i < 16; i += 4) {
    f32x4 av = {acc[i], acc[i + 1], acc[i + 2], acc[i + 3]};
    *(f32x4*)&sm[w][c0 + i] = av;
  }
  __syncthreads();
  {
    int cc = t * 4;
    f32x4 m0 = *(const f32x4*)&sm[0][cc];
    f32x4 m1 = *(const f32x4*)&sm[1][cc];
    f32x4 m2 = *(const f32x4*)&sm[2][cc];
    f32x4 m3 = *(const f32x4*)&sm[3][cc];
    ushort o[4];
#pragma unroll
    for (int j = 0; j < 4; j++)
      o[j] = f2bf(fmaxf(fmaxf(m0[j], m1[j]), fmaxf(m2[j], m3[j])));
    uint2 uv = {(unsigned)o[0] | ((unsigned)o[1] << 16), (unsigned)o[2] | ((unsigned)o[3] << 16)};
    *(uint2*)(Xout + (size_t)bs * ld_out + cc) = uv;
  }
  if (prev_pts) {
    float p0 = prev_pts[(size_t)arow * pts_stride + 0];
    float p1 = prev_pts[(size_t)arow * pts_stride + 1];
    if (t == 0) {
      Xout[(size_t)bs * ld_out + 1024] = f2bf(p0);
      Xout[(size_t)bs * ld_out + 1025] = f2bf(p1);
      coords_out[bs * 2 + 0] = p0;
      coords_out[bs * 2 + 1] = p1;
    }
    if (t < 126) Xout[(size_t)bs * ld_out + 1026 + t] = 0;
  }
}

// ================= reduce K-split partials + bias; OUTBF: write bf16 ========================
template <int OUTBF>
__global__ __launch_bounds__(256) void k_reduce(int total, int Ncols, int nz,
                                                const float* __restrict__ part,
                                                const float* __restrict__ bias,
                                                void* __restrict__ out) {
  int i = blockIdx.x * 256 + threadIdx.x;
  if (i >= total) return;
  float s = bias[i % Ncols];
  for (int z = 0; z < nz; z++) s += part[(size_t)z * total + i];
  if (OUTBF)
    ((ushort*)out)[i] = f2bf(s);
  else
    ((float*)out)[i] = s;
}

// ================= launch ====================================================================
extern "C" void kernel_launch(void* const* d_in, const int* in_sizes, int n_in, void* d_out,
                              int out_size, void* d_ws, size_t ws_size, hipStream_t stream) {
  (void)in_sizes; (void)n_in; (void)out_size; (void)ws_size;
  const float* points = (const float*)d_in[0];
  const float* feat_map = (const float*)d_in[1];
  const float* dw0 = (const float*)d_in[2];
  const float* db0 = (const float*)d_in[3];
  const float* aw0 = (const float*)d_in[4];
  const float* ab0 = (const float*)d_in[5];
  const float* lg0 = (const float*)d_in[6];
  const float* lb0 = (const float*)d_in[7];
  const float* dw1 = (const float*)d_in[8];
  const float* db1 = (const float*)d_in[9];
  const float* aw1 = (const float*)d_in[10];
  const float* ab1 = (const float*)d_in[11];
  const float* lg1 = (const float*)d_in[12];
  const float* lb1 = (const float*)d_in[13];
  const float* fw = (const float*)d_in[14];
  const float* fb = (const float*)d_in[15];
  const float* dmw = (const float*)d_in[16];
  const float* dmb = (const float*)d_in[17];
  float* out = (float*)d_out;

  char* wsb = (char*)d_ws;
  size_t off = 0;
  auto alloc = [&](size_t bytes) -> void* {
    void* p = wsb + off;
    off = (off + bytes + 255) & ~(size_t)255;
    return p;
  };
  float* fmT = (float*)alloc((size_t)1024 * 1024 * 4);
  ushort* Xb0 = (ushort*)alloc((size_t)B_ * N_ * LDP_ * 2);
  ushort* Gb = (ushort*)alloc((size_t)B_ * N_ * C_ * 2);
  ushort* Pb = (ushort*)alloc((size_t)B_ * S0_ * C_ * 2);
  ushort* Xb1 = (ushort*)alloc((size_t)B_ * S0_ * LDP_ * 2);
  ushort* fts2b = (ushort*)alloc((size_t)B_ * S1_ * C_ * 2);
  float* coords1 = (float*)alloc((size_t)B_ * S0_ * 2 * 4);
  ushort* awdb0 = (ushort*)alloc((size_t)C_ * LDP_ * 2);
  ushort* awab0 = (ushort*)alloc((size_t)C_ * LDP_ * 2);
  ushort* awdb1 = (ushort*)alloc((size_t)C_ * LDP_ * 2);
  ushort* awab1 = (ushort*)alloc((size_t)C_ * LDP_ * 2);
  ushort* dwT0 = (ushort*)alloc((size_t)LDP_ * LDP_ * 2);
  ushort* dwT1 = (ushort*)alloc((size_t)LDP_ * LDP_ * 2);
  ushort* Wcb0 = (ushort*)alloc((size_t)C_ * LDP_ * 2);
  ushort* Wcb1 = (ushort*)alloc((size_t)C_ * LDP_ * 2);
  float* dvp0 = (float*)alloc(1024 * 4);
  float* dvp1 = (float*)alloc(1024 * 4);
  int* rows0 = (int*)alloc(B_ * S0_ * 4);
  int* nn0 = (int*)alloc(B_ * S0_ * K_ * 4);
  int* rows1 = (int*)alloc(B_ * S1_ * 4);
  int* nn1 = (int*)alloc(B_ * S1_ * K_ * 4);
  float* hpart = (float*)alloc((size_t)32 * B_ * C_ * 4);
  ushort* hidb = (ushort*)alloc((size_t)B_ * C_ * 2);
  float* opart = (float*)alloc((size_t)4 * B_ * OUT_ * 4);

  // 1) weight prep + feat_map transpose
  k_prep<<<PREP_TOTAL, 256, 0, stream>>>(aw0, aw1, dw0, dw1, db0, ab0, db1, ab1, feat_map, awdb0,
                                         awab0, awdb1, awab1, dwT0, dwT1, dvp0, dvp1, fmT);
  // 2) FPS0 (prio 3, DS-free) || Wc combine GEMMs || bilinear sample
  k_wc_bil<<<32 + 144 + B_ * N_, 256, 0, stream>>>(awdb0, dwT0, Wcb0, awdb1, dwT1, Wcb1, points,
                                                   fmT, Xb0, rows0);
  // 3) stage 0: G0 big || P0 big || kNN0 (512-thread blocks; 1792 = 512+256+1024)
  k_stage0<<<1792, 512, 0, stream>>>(Xb0, Wcb0, Gb, rows0, awab0, dvp0, Pb, points, nn0);
  // 4) fused stage 0 (XCD-chunked swizzle)
  k_fused_stage<<<B_ * S0_, 256, 0, stream>>>(Gb, Pb, rows0, nn0, lg0, lb0, points, 2, Xb1, LDP_,
                                              coords1);
  // 5) stage 1: FPS1 (prio 3) || G1 big (512-thread blocks)
  k_gemm_fps1<<<32 + 256, 512, 0, stream>>>(Xb1, Wcb1, Gb, coords1, rows1);
  // 6) stage 1: P1 big || kNN1 (512-thread blocks; 320 = 64 + 256)
  k_p1_knn1<<<320, 512, 0, stream>>>(Xb1, rows1, awab1, dvp1, Pb, coords1, nn1);
  // 7) fused stage 1 (XCD-chunked swizzle)
  k_fused_stage<<<B_ * S1_, 256, 0, stream>>>(Gb, Pb, rows1, nn1, lg1, lb1, nullptr, 0, fts2b, C_,
                                              nullptr);
  // 8) flat head (fused f32 W conversion), K-split 32 x 2048
  {
    dim3 g(8, 1, 32);
    k_flat<<<g, 256, 0, stream>>>(fts2b, fw, hpart);
  }
  // 9) reduce -> hid (bf16)
  k_reduce<1><<<(B_ * C_ + 255) / 256, 256, 0, stream>>>(B_ * C_, C_, 32, hpart, fb, hidb);
  // 10) dim head (fused f32 dmw conversion), z-split 4 x 256
  {
    dim3 g(28, 1, 4);
    k_dim<<<g, 256, 0, stream>>>(hidb, dmw, opart);
  }
  // 11) reduce -> out
  k_reduce<0><<<(B_ * OUT_ + 255) / 256, 256, 0, stream>>>(B_ * OUT_, OUT_, 4, opart, dmb, out);
}

// Round 20
// 416.738 us; speedup vs baseline: 1.0224x; 1.0224x over previous
//
#include <hip/hip_runtime.h>
#include <cstdint>
#include <cstddef>

// ---------------- constants ----------------
static const int B_ = 32, N_ = 512, C_ = 1024, C2_ = 1026, CC2_ = 2052;
static const int S0_ = 256, S1_ = 64, K_ = 16, OUT_ = 3584;
static const int LDP_ = 1152;   // padded row stride (multiple of 128 and 64)
static const int KEFF_ = 1088;  // 17*64 >= C2_; cols [1026,1088) are zeros -> bit-identical

typedef unsigned short ushort;
typedef __attribute__((ext_vector_type(8))) short short8;
typedef __attribute__((ext_vector_type(4))) float f32x4;

__device__ __forceinline__ ushort f2bf(float x) {
  unsigned u = __float_as_uint(x);
  unsigned r = (u + 0x7fffu + ((u >> 16) & 1u)) >> 16;
  return (ushort)r;
}
__device__ __forceinline__ float bf2f(ushort b) {
  return __uint_as_float(((unsigned)b) << 16);
}

__device__ __forceinline__ void gload16(const void* g, void* l) {
  __builtin_amdgcn_global_load_lds((const __attribute__((address_space(1))) void*)g,
                                   (__attribute__((address_space(3))) void*)l, 16, 0, 0);
}

// ---- DS-free wave-64 unsigned-max reduce via DPP; result valid in lane 63 ----
__device__ __forceinline__ unsigned wave_umax_dpp(unsigned v) {
  unsigned t;
  t = (unsigned)__builtin_amdgcn_update_dpp(0, (int)v, 0x111, 0xf, 0xf, true);  // row_shr:1
  v = v > t ? v : t;
  t = (unsigned)__builtin_amdgcn_update_dpp(0, (int)v, 0x112, 0xf, 0xf, true);  // row_shr:2
  v = v > t ? v : t;
  t = (unsigned)__builtin_amdgcn_update_dpp(0, (int)v, 0x114, 0xf, 0xf, true);  // row_shr:4
  v = v > t ? v : t;
  t = (unsigned)__builtin_amdgcn_update_dpp(0, (int)v, 0x118, 0xf, 0xf, true);  // row_shr:8
  v = v > t ? v : t;
  t = (unsigned)__builtin_amdgcn_update_dpp(0, (int)v, 0x142, 0xf, 0xf, true);  // row_bcast15
  v = v > t ? v : t;
  t = (unsigned)__builtin_amdgcn_update_dpp(0, (int)v, 0x143, 0xf, 0xf, true);  // row_bcast31
  v = v > t ? v : t;
  return v;
}

// ================= device GEMM (128x128 tile, 4 waves, 16x16x32 MFMA, BK=64 two-half) ========
// OMODE 1: bf16 out, zero for c>=Neff. OMODE 2: bf16 out + f32 bias.
template <int OMODE>
__device__ __forceinline__ void dev_mgemm(int bx, int by, ushort* As, ushort* Bs, int M, int Neff,
                                          int K, const ushort* __restrict__ A, int lda,
                                          const int* __restrict__ rowidx,
                                          const ushort* __restrict__ Wt, int ldw,
                                          const float* __restrict__ bias,
                                          void* __restrict__ Cout, int ldc) {
  int t = threadIdx.x;
  int w = t >> 6, l = t & 63;
  int row0 = by * 128, col0 = bx * 128;
  f32x4 acc[4][4];
#pragma unroll
  for (int i = 0; i < 4; i++)
#pragma unroll
    for (int j = 0; j < 4; j++) acc[i][j] = (f32x4){0.f, 0.f, 0.f, 0.f};

  int srow = l >> 2;       // 0..15
  int scol = (l & 3) * 8;  // 0,8,16,24
  int ar0 = min(row0 + w * 16 + srow, M - 1);
  int ar1 = min(row0 + 64 + w * 16 + srow, M - 1);
  if (rowidx) { ar0 = rowidx[ar0]; ar1 = rowidx[ar1]; }
  const ushort* gA0 = A + (size_t)ar0 * lda + scol;
  const ushort* gA1 = A + (size_t)ar1 * lda + scol;
  const ushort* gB0 = Wt + (size_t)(col0 + w * 16 + srow) * ldw + scol;
  const ushort* gB1 = Wt + (size_t)(col0 + 64 + w * 16 + srow) * ldw + scol;
  ushort* lA0 = As + w * 512;
  ushort* lA1 = As + 2048 + w * 512;
  ushort* lB0 = Bs + w * 512;
  ushort* lB1 = Bs + 2048 + w * 512;

  int wm = w >> 1, wn = w & 1;
  int fr = l & 15, fg = l >> 4;

  for (int kt = 0; kt < K; kt += 64) {
    __syncthreads();
    gload16(gA0 + kt, lA0);
    gload16(gA1 + kt, lA1);
    gload16(gB0 + kt, lB0);
    gload16(gB1 + kt, lB1);
    gload16(gA0 + kt + 32, lA0 + 4096);
    gload16(gA1 + kt + 32, lA1 + 4096);
    gload16(gB0 + kt + 32, lB0 + 4096);
    gload16(gB1 + kt + 32, lB1 + 4096);
    __syncthreads();
#pragma unroll
    for (int ks = 0; ks < 2; ks++) {
      short8 af[4], bf[4];
#pragma unroll
      for (int mi = 0; mi < 4; mi++)
        af[mi] = *(const short8*)&As[ks * 4096 + (wm * 64 + mi * 16 + fr) * 32 + fg * 8];
#pragma unroll
      for (int ni = 0; ni < 4; ni++)
        bf[ni] = *(const short8*)&Bs[ks * 4096 + (wn * 64 + ni * 16 + fr) * 32 + fg * 8];
#pragma unroll
      for (int mi = 0; mi < 4; mi++)
#pragma unroll
        for (int ni = 0; ni < 4; ni++)
          acc[mi][ni] =
              __builtin_amdgcn_mfma_f32_16x16x32_bf16(af[mi], bf[ni], acc[mi][ni], 0, 0, 0);
    }
  }

  ushort* C = (ushort*)Cout;
  if (OMODE == 1) {
#pragma unroll
    for (int mi = 0; mi < 4; mi++)
#pragma unroll
      for (int ni = 0; ni < 4; ni++)
#pragma unroll
        for (int q = 0; q < 4; q++) {
          int r = row0 + wm * 64 + mi * 16 + fg * 4 + q;
          int c = col0 + wn * 64 + ni * 16 + fr;
          if (r < M) C[(size_t)r * ldc + c] = f2bf(c < Neff ? acc[mi][ni][q] : 0.f);
        }
  } else {
#pragma unroll
    for (int mi = 0; mi < 4; mi++)
#pragma unroll
      for (int ni = 0; ni < 4; ni++)
#pragma unroll
        for (int q = 0; q < 4; q++) {
          int r = row0 + wm * 64 + mi * 16 + fg * 4 + q;
          int c = col0 + wn * 64 + ni * 16 + fr;
          if (r < M) C[(size_t)r * ldc + c] = f2bf(acc[mi][ni][q] + bias[c]);
        }
  }
}

// ================= device GEMM BIG (256x128 tile, 8 waves / 512 threads, BK=64 two-half) =====
// A staged twice, B once per half -> 25% less staging per MFMA; (kt,ks) order identical to
// dev_mgemm -> bit-identical accumulation. As: 16384 ushorts, Bs: 8192 ushorts (48KB LDS).
template <int OMODE>
__device__ __forceinline__ void dev_mgemm_big(int bx, int by, ushort* As, ushort* Bs, int M,
                                              int Neff, int K, const ushort* __restrict__ A,
                                              int lda, const int* __restrict__ rowidx,
                                              const ushort* __restrict__ Wt, int ldw,
                                              const float* __restrict__ bias,
                                              void* __restrict__ Cout, int ldc) {
  int t = threadIdx.x;
  int w = t >> 6, l = t & 63;
  int row0 = by * 256, col0 = bx * 128;
  f32x4 acc[4][4];
#pragma unroll
  for (int i = 0; i < 4; i++)
#pragma unroll
    for (int j = 0; j < 4; j++) acc[i][j] = (f32x4){0.f, 0.f, 0.f, 0.f};

  int srow = l >> 2;       // 0..15
  int scol = (l & 3) * 8;  // 0,8,16,24
  int ar0 = min(row0 + w * 16 + srow, M - 1);        // rows 0..127
  int ar1 = min(row0 + 128 + w * 16 + srow, M - 1);  // rows 128..255
  if (rowidx) { ar0 = rowidx[ar0]; ar1 = rowidx[ar1]; }
  const ushort* gA0 = A + (size_t)ar0 * lda + scol;
  const ushort* gA1 = A + (size_t)ar1 * lda + scol;
  const ushort* gB0 = Wt + (size_t)(col0 + w * 16 + srow) * ldw + scol;  // 8 waves = 128 rows
  ushort* lA0 = As + w * 512;         // rows 0..127 of half
  ushort* lA1 = As + 4096 + w * 512;  // rows 128..255 of half
  ushort* lB0 = Bs + w * 512;         // all 128 B rows

  int wm = w >> 1, wn = w & 1;  // wm 0..3 (64-row slab), wn 0..1 (64-col slab)
  int fr = l & 15, fg = l >> 4;

  for (int kt = 0; kt < K; kt += 64) {
    __syncthreads();
    gload16(gA0 + kt, lA0);
    gload16(gA1 + kt, lA1);
    gload16(gB0 + kt, lB0);
    gload16(gA0 + kt + 32, lA0 + 8192);
    gload16(gA1 + kt + 32, lA1 + 8192);
    gload16(gB0 + kt + 32, lB0 + 4096);
    __syncthreads();
#pragma unroll
    for (int ks = 0; ks < 2; ks++) {
      short8 af[4], bf[4];
#pragma unroll
      for (int mi = 0; mi < 4; mi++)
        af[mi] = *(const short8*)&As[ks * 8192 + (wm * 64 + mi * 16 + fr) * 32 + fg * 8];
#pragma unroll
      for (int ni = 0; ni < 4; ni++)
        bf[ni] = *(const short8*)&Bs[ks * 4096 + (wn * 64 + ni * 16 + fr) * 32 + fg * 8];
#pragma unroll
      for (int mi = 0; mi < 4; mi++)
#pragma unroll
        for (int ni = 0; ni < 4; ni++)
          acc[mi][ni] =
              __builtin_amdgcn_mfma_f32_16x16x32_bf16(af[mi], bf[ni], acc[mi][ni], 0, 0, 0);
    }
  }

  ushort* C = (ushort*)Cout;
  if (OMODE == 1) {
#pragma unroll
    for (int mi = 0; mi < 4; mi++)
#pragma unroll
      for (int ni = 0; ni < 4; ni++)
#pragma unroll
        for (int q = 0; q < 4; q++) {
          int r = row0 + wm * 64 + mi * 16 + fg * 4 + q;
          int c = col0 + wn * 64 + ni * 16 + fr;
          if (r < M) C[(size_t)r * ldc + c] = f2bf(c < Neff ? acc[mi][ni][q] : 0.f);
        }
  } else {
#pragma unroll
    for (int mi = 0; mi < 4; mi++)
#pragma unroll
      for (int ni = 0; ni < 4; ni++)
#pragma unroll
        for (int q = 0; q < 4; q++) {
          int r = row0 + wm * 64 + mi * 16 + fg * 4 + q;
          int c = col0 + wn * 64 + ni * 16 + fr;
          if (r < M) C[(size_t)r * ldc + c] = f2bf(acc[mi][ni][q] + bias[c]);
        }
  }
}

// ================= device FPS: DS-free (DPP reduce + readlane broadcast), prio 3 =============
template <int NPL>
__device__ __forceinline__ void dev_fps(int b, int Np, int nsub, const float* __restrict__ pts,
                                        int stride, int* __restrict__ rows) {
  __builtin_amdgcn_s_setprio(3);
  int lane = threadIdx.x;  // caller guarantees < 64
  const float* pb = pts + (size_t)b * Np * stride;
  float px[NPL], py[NPL], dist[NPL];
#pragma unroll
  for (int i = 0; i < NPL; i++) {
    int j = lane + 64 * i;
    px[i] = pb[(size_t)j * stride + 0];
    py[i] = pb[(size_t)j * stride + 1];
    dist[i] = 1e10f;
  }
  int far = 0;
  float fx = pb[0], fy = pb[1];
  for (int s = 0; s < nsub; s++) {
    if (lane == 0) rows[b * nsub + s] = b * Np + far;
    unsigned bd = 0;
    int bidx = lane;
#pragma unroll
    for (int i = 0; i < NPL; i++) {
      float dx = __fsub_rn(px[i], fx), dy = __fsub_rn(py[i], fy);
      float d = __fadd_rn(__fmul_rn(dx, dx), __fmul_rn(dy, dy));
      dist[i] = fminf(dist[i], d);
      unsigned db = __float_as_uint(dist[i]);
      if (i == 0) {
        bd = db;
      } else if (db > bd) {
        bd = db;
        bidx = lane + 64 * i;
      }
    }
    unsigned maxd = (unsigned)__builtin_amdgcn_readlane((int)wave_umax_dpp(bd), 63);
    unsigned cand = (bd == maxd) ? ~(unsigned)bidx : 0u;
    far = (int)~(unsigned)__builtin_amdgcn_readlane((int)wave_umax_dpp(cand), 63);
    int chunk = far >> 6, owner = far & 63;
    float cx = px[0], cy = py[0];
#pragma unroll
    for (int i = 1; i < NPL; i++) {
      bool cnd = (chunk == i);
      cx = cnd ? px[i] : cx;
      cy = cnd ? py[i] : cy;
    }
    fx = __uint_as_float((unsigned)__builtin_amdgcn_readlane((int)__float_as_uint(cx), owner));
    fy = __uint_as_float((unsigned)__builtin_amdgcn_readlane((int)__float_as_uint(cy), owner));
  }
  __builtin_amdgcn_s_setprio(0);
}

// ================= device kNN: DS-free (DPP min via complemented max) =======================
template <int NPL>
__device__ __forceinline__ void dev_knn(int bs, int S, int Np, const float* __restrict__ pts,
                                        int stride, const int* __restrict__ rows,
                                        int* __restrict__ nn) {
  int b = bs / S;
  int lane = threadIdx.x & 63;
  const float* pb = pts + (size_t)b * Np * stride;
  int arow = rows[bs];
  float ax = pts[(size_t)arow * stride + 0];
  float ay = pts[(size_t)arow * stride + 1];
  unsigned d2[NPL];
#pragma unroll
  for (int i = 0; i < NPL; i++) {
    int j = lane + 64 * i;
    float dx = __fsub_rn(ax, pb[(size_t)j * stride + 0]);
    float dy = __fsub_rn(ay, pb[(size_t)j * stride + 1]);
    d2[i] = __float_as_uint(__fadd_rn(__fmul_rn(dx, dx), __fmul_rn(dy, dy)));
  }
  unsigned mask = 0;
  for (int k = 0; k < K_; k++) {
    unsigned bd = 0xFFFFFFFFu;
    int bidx = 0x7fffffff;
#pragma unroll
    for (int i = 0; i < NPL; i++) {
      int j = lane + 64 * i;
      bool used = (mask >> i) & 1u;
      if (!used && (d2[i] < bd || (d2[i] == bd && j < bidx))) { bd = d2[i]; bidx = j; }
    }
    unsigned mind = ~(unsigned)__builtin_amdgcn_readlane((int)wave_umax_dpp(~bd), 63);
    unsigned cand = (bd == mind) ? ~(unsigned)bidx : 0u;
    int bi = (int)~(unsigned)__builtin_amdgcn_readlane((int)wave_umax_dpp(cand), 63);
    if ((bi & 63) == lane) mask |= 1u << (bi >> 6);
    if (lane == 0) nn[bs * K_ + k] = b * Np + bi;
  }
}

// ================= device bilinear ===========================================================
__device__ __forceinline__ void dev_bilinear(int r, const float* __restrict__ points,
                                             const float* __restrict__ fmT,
                                             ushort* __restrict__ X0) {
  float p0 = points[r * 2 + 0], p1 = points[r * 2 + 1];
  float g0 = __fsub_rn(__fmul_rn(2.0f, p1), 1.0f);
  float g1 = __fsub_rn(__fmul_rn(2.0f, p0), 1.0f);
  float x = __fmul_rn(__fmul_rn(__fadd_rn(g0, 1.0f), 0.5f), 31.0f);
  float y = __fmul_rn(__fmul_rn(__fadd_rn(g1, 1.0f), 0.5f), 31.0f);
  float x0f = floorf(x), y0f = floorf(y);
  float wx = __fsub_rn(x, x0f), wy = __fsub_rn(y, y0f);
  int x0i = (int)fminf(fmaxf(x0f, 0.f), 31.f);
  int x1i = (int)fminf(fmaxf(__fadd_rn(x0f, 1.f), 0.f), 31.f);
  int y0i = (int)fminf(fmaxf(y0f, 0.f), 31.f);
  int y1i = (int)fminf(fmaxf(__fadd_rn(y0f, 1.f), 0.f), 31.f);
  float omwx = __fsub_rn(1.f, wx), omwy = __fsub_rn(1.f, wy);
  size_t i00 = (size_t)(y0i * 32 + x0i) * 1024;
  size_t i01 = (size_t)(y0i * 32 + x1i) * 1024;
  size_t i10 = (size_t)(y1i * 32 + x0i) * 1024;
  size_t i11 = (size_t)(y1i * 32 + x1i) * 1024;
  int t = threadIdx.x;
  int c0 = t * 4;
  ushort* xr = X0 + (size_t)r * LDP_;
  float4 f00 = *(const float4*)(fmT + i00 + c0);
  float4 f01 = *(const float4*)(fmT + i01 + c0);
  float4 f10 = *(const float4*)(fmT + i10 + c0);
  float4 f11 = *(const float4*)(fmT + i11 + c0);
  float a[4] = {f00.x, f00.y, f00.z, f00.w};
  float b[4] = {f01.x, f01.y, f01.z, f01.w};
  float c[4] = {f10.x, f10.y, f10.z, f10.w};
  float d[4] = {f11.x, f11.y, f11.z, f11.w};
  ushort o[4];
#pragma unroll
  for (int i = 0; i < 4; i++) {
    float t1 = a[i] * omwx * omwy;
    float t2 = b[i] * wx * omwy;
    float t3 = c[i] * omwx * wy;
    float t4 = d[i] * wx * wy;
    o[i] = f2bf(((t1 + t2) + t3) + t4);
  }
  uint2 uv = {(unsigned)o[0] | ((unsigned)o[1] << 16), (unsigned)o[2] | ((unsigned)o[3] << 16)};
  *(uint2*)(xr + c0) = uv;
  if (t == 0) { xr[1024] = f2bf(p0); xr[1025] = f2bf(p1); }
  if (t < 126) xr[1026 + t] = 0;
}

// ================= merged weight prep: aw cvts + dw transposes + dvec + fm transpose =========
static const int PREP_CVT = 2304;  // per aw job: 1024*1152/2/256
static const int PREP_TT = 1296;   // 36x36 tiles
static const int PREP_FMT = 1024;  // 32x32 tiles of feat_map
static const int PREP_TOTAL = 4 * PREP_CVT + 2 * PREP_TT + 512 + PREP_FMT;

__global__ __launch_bounds__(256) void k_prep(
    const float* __restrict__ aw0, const float* __restrict__ aw1, const float* __restrict__ dw0,
    const float* __restrict__ dw1, const float* __restrict__ db0, const float* __restrict__ ab0,
    const float* __restrict__ db1, const float* __restrict__ ab1,
    const float* __restrict__ feat_map, ushort* __restrict__ awdb0, ushort* __restrict__ awab0,
    ushort* __restrict__ awdb1, ushort* __restrict__ awab1, ushort* __restrict__ dwT0,
    ushort* __restrict__ dwT1, float* __restrict__ dvp0, float* __restrict__ dvp1,
    float* __restrict__ fmT) {
  __shared__ float tile[32][33];
  int bid = blockIdx.x;
  if (bid < 4 * PREP_CVT) {
    int job = bid / PREP_CVT, lb = bid % PREP_CVT;
    const float* src = (job < 2) ? aw0 : aw1;
    int soff = (job & 1) ? C2_ : 0;
    ushort* dst = (job == 0) ? awdb0 : (job == 1) ? awab0 : (job == 2) ? awdb1 : awab1;
    unsigned e = (lb * 256u + threadIdx.x) * 2u;
    unsigned r = e / (unsigned)LDP_, c = e % (unsigned)LDP_;
    float v0 = 0.f, v1 = 0.f;
    const float* sp = src + (size_t)r * CC2_ + soff + c;
    if ((int)c < C2_) v0 = sp[0];
    if ((int)(c + 1) < C2_) v1 = sp[1];
    *(unsigned*)(dst + e) = (unsigned)f2bf(v0) | ((unsigned)f2bf(v1) << 16);
    return;
  }
  bid -= 4 * PREP_CVT;
  if (bid < 2 * PREP_TT) {
    int which = bid / PREP_TT, id = bid % PREP_TT;
    const float* src = which ? dw1 : dw0;
    ushort* dst = which ? dwT1 : dwT0;
    int bx = (id % 36) * 32, by = (id / 36) * 32;
    int tx = threadIdx.x & 31, ty4 = (threadIdx.x >> 5) * 4;
#pragma unroll
    for (int i = 0; i < 4; i++) {
      int r = by + ty4 + i, c = bx + tx;
      tile[ty4 + i][tx] = (r < C2_ && c < C2_) ? src[(size_t)r * C2_ + c] : 0.f;
    }
    __syncthreads();
#pragma unroll
    for (int i = 0; i < 4; i++)
      dst[(size_t)(bx + ty4 + i) * LDP_ + by + tx] = f2bf(tile[tx][ty4 + i]);
    return;
  }
  bid -= 2 * PREP_TT;
  if (bid < 512) {
    int which = bid >> 8;
    int cb = bid & 255;
    const float* aw = which ? aw1 : aw0;
    const float* db = which ? db1 : db0;
    const float* ab = which ? ab1 : ab0;
    float* dvp = which ? dvp1 : dvp0;
    int w = threadIdx.x >> 6, lane = threadIdx.x & 63;
    int c = cb * 4 + w;
    const float* wr = aw + (size_t)c * CC2_;
    float s = 0.f;
    for (int d = lane; d < C2_; d += 64) s += db[d] * wr[d];
#pragma unroll
    for (int off = 32; off; off >>= 1) s += __shfl_xor(s, off);
    if (lane == 0) dvp[c] = ab[c] + s;
    return;
  }
  bid -= 512;
  {
    int yx0 = (bid & 31) * 32, c0 = (bid >> 5) * 32;
    int tx = threadIdx.x & 31, ty = threadIdx.x >> 5;
#pragma unroll
    for (int i = 0; i < 4; i++)
      tile[ty + 8 * i][tx] = feat_map[(size_t)(c0 + ty + 8 * i) * 1024 + yx0 + tx];
    __syncthreads();
#pragma unroll
    for (int i = 0; i < 4; i++)
      fmT[(size_t)(yx0 + ty + 8 * i) * 1024 + c0 + tx] = tile[tx][ty + 8 * i];
  }
}

// ================= merged: FPS0 (prio 3, DS-free) + Wc combine GEMMs + bilinear =============
__global__ __launch_bounds__(256) void k_wc_bil(
    const ushort* __restrict__ awdb0, const ushort* __restrict__ dwT0, ushort* __restrict__ Wcb0,
    const ushort* __restrict__ awdb1, const ushort* __restrict__ dwT1, ushort* __restrict__ Wcb1,
    const float* __restrict__ points, const float* __restrict__ fmT, ushort* __restrict__ Xb0,
    int* __restrict__ rows0) {
  __shared__ ushort As[8192];
  __shared__ ushort Bs[8192];
  int bid = blockIdx.x;
  if (bid < 32) {
    if (threadIdx.x < 64) dev_fps<8>(bid, N_, S0_, points, 2, rows0);
    return;
  }
  bid -= 32;
  if (bid < 72) {
    dev_mgemm<1>(bid / 8, bid % 8, As, Bs, C_, C2_, KEFF_, awdb0, LDP_, nullptr, dwT0, LDP_,
                 nullptr, Wcb0, LDP_);
  } else if (bid < 144) {
    int b2 = bid - 72;
    dev_mgemm<1>(b2 / 8, b2 % 8, As, Bs, C_, C2_, KEFF_, awdb1, LDP_, nullptr, dwT1, LDP_, nullptr,
                 Wcb1, LDP_);
  } else {
    dev_bilinear(bid - 144, points, fmT, Xb0);
  }
}

// ================= merged stage 0 (512 threads): G0 big + P0 big + kNN0 =====================
// blocks: [0,512) G0 (nrb=64) | [512,768) P0 (nrb=32) | [768,1792) kNN0 (8 q/block = 8192)
__global__ __launch_bounds__(512) void k_stage0(
    const ushort* __restrict__ Xb0, const ushort* __restrict__ Wcb0, ushort* __restrict__ Gb,
    const int* __restrict__ rows0, const ushort* __restrict__ awab0,
    const float* __restrict__ dvp0, ushort* __restrict__ Pb, const float* __restrict__ points,
    int* __restrict__ nn0) {
  __shared__ ushort As[16384];
  __shared__ ushort Bs[8192];
  int bid = blockIdx.x;
  if (bid < 512) {
    dev_mgemm_big<1>(bid / 64, bid % 64, As, Bs, B_ * N_, C_, KEFF_, Xb0, LDP_, nullptr, Wcb0,
                     LDP_, nullptr, Gb, C_);
    return;
  }
  if (bid < 768) {
    int b2 = bid - 512;
    dev_mgemm_big<2>(b2 / 32, b2 % 32, As, Bs, B_ * S0_, C_, KEFF_, Xb0, LDP_, rows0, awab0, LDP_,
                     dvp0, Pb, C_);
    return;
  }
  int w = threadIdx.x >> 6;
  int qid = (bid - 768) * 8 + w;  // 1024 blocks x 8 waves = 8192 queries
  dev_knn<8>(qid, S0_, N_, points, 2, rows0, nn0);
}

// ================= merged stage 1 (512 threads): FPS1 + G1 big ==============================
// blocks: [0,32) FPS1 | [32,288) G1 (nrb=32)
__global__ __launch_bounds__(512) void k_gemm_fps1(const ushort* __restrict__ Xb1,
                                                   const ushort* __restrict__ Wcb1,
                                                   ushort* __restrict__ Gout,
                                                   const float* __restrict__ coords1,
                                                   int* __restrict__ rows1) {
  __shared__ ushort As[16384];
  __shared__ ushort Bs[8192];
  int bid = blockIdx.x;
  if (bid < 32) {
    if (threadIdx.x < 64) dev_fps<4>(bid, S0_, S1_, coords1, 2, rows1);
    return;
  }
  int b2 = bid - 32;
  dev_mgemm_big<1>(b2 / 32, b2 % 32, As, Bs, B_ * S0_, C_, KEFF_, Xb1, LDP_, nullptr, Wcb1, LDP_,
                   nullptr, Gout, C_);
}

// ================= merged: P-GEMM (XCD row-major) + kNN (4 queries/block) ===================
template <int NPL>
__global__ __launch_bounds__(256) void k_gemm_knn(int nrb, int Mp, const ushort* __restrict__ A,
                                                  int lda, const int* __restrict__ rowsA,
                                                  const ushort* __restrict__ Wt,
                                                  const float* __restrict__ bias,
                                                  ushort* __restrict__ Pout, int ngemm, int S,
                                                  int Np, const float* __restrict__ pts,
                                                  int stride, const int* __restrict__ rows,
                                                  int* __restrict__ nn) {
  __shared__ ushort As[8192];
  __shared__ ushort Bs[8192];
  int bid = blockIdx.x;
  if (bid < ngemm) {
    dev_mgemm<2>(bid / nrb, bid % nrb, As, Bs, Mp, C_, KEFF_, A, lda, rowsA, Wt, LDP_, bias, Pout,
                 C_);
  } else {
    int w = threadIdx.x >> 6;
    int qid = (bid - ngemm) * 4 + w;
    dev_knn<NPL>(qid, S, Np, pts, stride, rows, nn);
  }
}

// ================= flat head GEMM with fused f32->bf16 W conversion =========================
__global__ __launch_bounds__(256) void k_flat(const ushort* __restrict__ A,  // [32][65536] bf16
                                              const float* __restrict__ W,   // [1024][65536] f32
                                              float* __restrict__ Cp) {      // [32][32][1024]
  int t = threadIdx.x;
  int w = t >> 6, l = t & 63;
  int fr = l & 15, fg = l >> 4;
  int col0 = blockIdx.x * 128 + w * 32;
  size_t k0 = (size_t)blockIdx.z * 2048;
  f32x4 acc[2][2];
#pragma unroll
  for (int i = 0; i < 2; i++)
#pragma unroll
    for (int j = 0; j < 2; j++) acc[i][j] = (f32x4){0.f, 0.f, 0.f, 0.f};
  const ushort* a0 = A + (size_t)fr * 65536 + k0 + fg * 8;
  const ushort* a1 = A + (size_t)(16 + fr) * 65536 + k0 + fg * 8;
  const float* b0 = W + (size_t)(col0 + fr) * 65536 + k0 + fg * 8;
  const float* b1 = W + (size_t)(col0 + 16 + fr) * 65536 + k0 + fg * 8;
  for (int kt = 0; kt < 2048; kt += 32) {
    short8 af0 = *(const short8*)(a0 + kt);
    short8 af1 = *(const short8*)(a1 + kt);
    float4 p0 = *(const float4*)(b0 + kt);
    float4 p1 = *(const float4*)(b0 + kt + 4);
    float4 q0 = *(const float4*)(b1 + kt);
    float4 q1 = *(const float4*)(b1 + kt + 4);
    short8 bf0, bf1;
    bf0[0] = (short)f2bf(p0.x); bf0[1] = (short)f2bf(p0.y);
    bf0[2] = (short)f2bf(p0.z); bf0[3] = (short)f2bf(p0.w);
    bf0[4] = (short)f2bf(p1.x); bf0[5] = (short)f2bf(p1.y);
    bf0[6] = (short)f2bf(p1.z); bf0[7] = (short)f2bf(p1.w);
    bf1[0] = (short)f2bf(q0.x); bf1[1] = (short)f2bf(q0.y);
    bf1[2] = (short)f2bf(q0.z); bf1[3] = (short)f2bf(q0.w);
    bf1[4] = (short)f2bf(q1.x); bf1[5] = (short)f2bf(q1.y);
    bf1[6] = (short)f2bf(q1.z); bf1[7] = (short)f2bf(q1.w);
    acc[0][0] = __builtin_amdgcn_mfma_f32_16x16x32_bf16(af0, bf0, acc[0][0], 0, 0, 0);
    acc[1][0] = __builtin_amdgcn_mfma_f32_16x16x32_bf16(af1, bf0, acc[1][0], 0, 0, 0);
    acc[0][1] = __builtin_amdgcn_mfma_f32_16x16x32_bf16(af0, bf1, acc[0][1], 0, 0, 0);
    acc[1][1] = __builtin_amdgcn_mfma_f32_16x16x32_bf16(af1, bf1, acc[1][1], 0, 0, 0);
  }
  float* Cz = Cp + (size_t)blockIdx.z * 32 * 1024;
#pragma unroll
  for (int mi = 0; mi < 2; mi++)
#pragma unroll
    for (int ni = 0; ni < 2; ni++)
#pragma unroll
      for (int q = 0; q < 4; q++) {
        int r = mi * 16 + fg * 4 + q;
        int c = col0 + ni * 16 + fr;
        Cz[(size_t)r * 1024 + c] = acc[mi][ni][q];
      }
}

// ================= dim head GEMM (z-split 4 x 256) with fused f32->bf16 W conversion ========
__global__ __launch_bounds__(256) void k_dim(const ushort* __restrict__ A,
                                             const float* __restrict__ W,
                                             float* __restrict__ Cp) {
  int t = threadIdx.x;
  int w = t >> 6, l = t & 63;
  int fr = l & 15, fg = l >> 4;
  int col0 = blockIdx.x * 128 + w * 32;
  int k0 = blockIdx.z * 256;
  f32x4 acc[2][2];
#pragma unroll
  for (int i = 0; i < 2; i++)
#pragma unroll
    for (int j = 0; j < 2; j++) acc[i][j] = (f32x4){0.f, 0.f, 0.f, 0.f};
  const ushort* a0 = A + (size_t)fr * 1024 + k0 + fg * 8;
  const ushort* a1 = A + (size_t)(16 + fr) * 1024 + k0 + fg * 8;
  const float* b0 = W + (size_t)(col0 + fr) * 1024 + k0 + fg * 8;
  const float* b1 = W + (size_t)(col0 + 16 + fr) * 1024 + k0 + fg * 8;
  for (int kt = 0; kt < 256; kt += 32) {
    short8 af0 = *(const short8*)(a0 + kt);
    short8 af1 = *(const short8*)(a1 + kt);
    float4 p0 = *(const float4*)(b0 + kt);
    float4 p1 = *(const float4*)(b0 + kt + 4);
    float4 q0 = *(const float4*)(b1 + kt);
    float4 q1 = *(const float4*)(b1 + kt + 4);
    short8 bf0, bf1;
    bf0[0] = (short)f2bf(p0.x); bf0[1] = (short)f2bf(p0.y);
    bf0[2] = (short)f2bf(p0.z); bf0[3] = (short)f2bf(p0.w);
    bf0[4] = (short)f2bf(p1.x); bf0[5] = (short)f2bf(p1.y);
    bf0[6] = (short)f2bf(p1.z); bf0[7] = (short)f2bf(p1.w);
    bf1[0] = (short)f2bf(q0.x); bf1[1] = (short)f2bf(q0.y);
    bf1[2] = (short)f2bf(q0.z); bf1[3] = (short)f2bf(q0.w);
    bf1[4] = (short)f2bf(q1.x); bf1[5] = (short)f2bf(q1.y);
    bf1[6] = (short)f2bf(q1.z); bf1[7] = (short)f2bf(q1.w);
    acc[0][0] = __builtin_amdgcn_mfma_f32_16x16x32_bf16(af0, bf0, acc[0][0], 0, 0, 0);
    acc[1][0] = __builtin_amdgcn_mfma_f32_16x16x32_bf16(af1, bf0, acc[1][0], 0, 0, 0);
    acc[0][1] = __builtin_amdgcn_mfma_f32_16x16x32_bf16(af0, bf1, acc[0][1], 0, 0, 0);
    acc[1][1] = __builtin_amdgcn_mfma_f32_16x16x32_bf16(af1, bf1, acc[1][1], 0, 0, 0);
  }
  float* Cz = Cp + (size_t)blockIdx.z * 32 * 3584;
#pragma unroll
  for (int mi = 0; mi < 2; mi++)
#pragma unroll
    for (int ni = 0; ni < 2; ni++)
#pragma unroll
      for (int q = 0; q < 4; q++) {
        int r = mi * 16 + fg * 4 + q;
        int c = col0 + ni * 16 + fr;
        Cz[(size_t)r * 3584 + c] = acc[mi][ni][q];
      }
}

// ================= fused stage: wave-per-k, barrier-free k-loop, XCD-chunked ================
__global__ __launch_bounds__(256) void k_fused_stage(
    const ushort* __restrict__ G, const ushort* __restrict__ Pb, const int* __restrict__ rows,
    const int* __restrict__ nn, const float* __restrict__ lng, const float* __restrict__ lnb,
    const float* __restrict__ prev_pts, int pts_stride, ushort* __restrict__ Xout, int ld_out,
    float* __restrict__ coords_out) {
  __shared__ float sm[4][1024];
  int chunk = (int)gridDim.x >> 3;
  int bs = (blockIdx.x & 7) * chunk + (blockIdx.x >> 3);
  int t = threadIdx.x;
  int w = t >> 6, lane = t & 63;
  int c0 = lane * 16;
  int arow = rows[bs];
  float base[16], lg[16], lb[16], acc[16];
  {
    short8 pA = *(const short8*)(Pb + (size_t)bs * C_ + c0);
    short8 pB = *(const short8*)(Pb + (size_t)bs * C_ + c0 + 8);
    short8 gA = *(const short8*)(G + (size_t)arow * C_ + c0);
    short8 gB = *(const short8*)(G + (size_t)arow * C_ + c0 + 8);
#pragma unroll
    for (int i = 0; i < 8; i++) {
      base[i] = bf2f((ushort)pA[i]) - bf2f((ushort)gA[i]);
      base[8 + i] = bf2f((ushort)pB[i]) - bf2f((ushort)gB[i]);
    }
#pragma unroll
    for (int i = 0; i < 4; i++) {
      float4 gv = *(const float4*)(lng + c0 + 4 * i);
      float4 bv = *(const float4*)(lnb + c0 + 4 * i);
      lg[4 * i] = gv.x; lg[4 * i + 1] = gv.y; lg[4 * i + 2] = gv.z; lg[4 * i + 3] = gv.w;
      lb[4 * i] = bv.x; lb[4 * i + 1] = bv.y; lb[4 * i + 2] = bv.z; lb[4 * i + 3] = bv.w;
      acc[4 * i] = -INFINITY; acc[4 * i + 1] = -INFINITY;
      acc[4 * i + 2] = -INFINITY; acc[4 * i + 3] = -INFINITY;
    }
  }
#pragma unroll
  for (int kk = 0; kk < 4; kk++) {
    int g = nn[bs * K_ + w * 4 + kk];
    const ushort* Gr = G + (size_t)g * C_ + c0;
    short8 xA = *(const short8*)(Gr);
    short8 xB = *(const short8*)(Gr + 8);
    float v[16];
    float s1 = 0.f, s2 = 0.f;
#pragma unroll
    for (int i = 0; i < 8; i++) {
      float x = fmaxf(bf2f((ushort)xA[i]) + base[i], 0.f);
      v[i] = x; s1 += x; s2 += x * x;
      float y = fmaxf(bf2f((ushort)xB[i]) + base[8 + i], 0.f);
      v[8 + i] = y; s1 += y; s2 += y * y;
    }
#pragma unroll
    for (int off = 32; off; off >>= 1) {
      s1 += __shfl_xor(s1, off);
      s2 += __shfl_xor(s2, off);
    }
    float mu = s1 * (1.f / 1024.f);
    float var = s2 * (1.f / 1024.f) - mu * mu;
    float rstd = 1.f / sqrtf(var + 1e-5f);
#pragma unroll
    for (int i = 0; i < 16; i++) {
      float nv = (v[i] - mu) * rstd * lg[i] + lb[i];
      acc[i] = fmaxf(acc[i], nv);
    }
  }
#pragma unroll
  for (int i = 0; i < 16; i += 4) {
    f32x4 av = {acc[i], acc[i + 1], acc[i + 2], acc[i + 3]};
    *(f32x4*)&sm[w][c0 + i] = av;
  }
  __syncthreads();
  {
    int cc = t * 4;
    f32x4 m0 = *(const f32x4*)&sm[0][cc];
    f32x4 m1 = *(const f32x4*)&sm[1][cc];
    f32x4 m2 = *(const f32x4*)&sm[2][cc];
    f32x4 m3 = *(const f32x4*)&sm[3][cc];
    ushort o[4];
#pragma unroll
    for (int j = 0; j < 4; j++)
      o[j] = f2bf(fmaxf(fmaxf(m0[j], m1[j]), fmaxf(m2[j], m3[j])));
    uint2 uv = {(unsigned)o[0] | ((unsigned)o[1] << 16), (unsigned)o[2] | ((unsigned)o[3] << 16)};
    *(uint2*)(Xout + (size_t)bs * ld_out + cc) = uv;
  }
  if (prev_pts) {
    float p0 = prev_pts[(size_t)arow * pts_stride + 0];
    float p1 = prev_pts[(size_t)arow * pts_stride + 1];
    if (t == 0) {
      Xout[(size_t)bs * ld_out + 1024] = f2bf(p0);
      Xout[(size_t)bs * ld_out + 1025] = f2bf(p1);
      coords_out[bs * 2 + 0] = p0;
      coords_out[bs * 2 + 1] = p1;
    }
    if (t < 126) Xout[(size_t)bs * ld_out + 1026 + t] = 0;
  }
}

// ================= reduce K-split partials + bias; OUTBF: write bf16 ========================
template <int OUTBF>
__global__ __launch_bounds__(256) void k_reduce(int total, int Ncols, int nz,
                                                const float* __restrict__ part,
                                                const float* __restrict__ bias,
                                                void* __restrict__ out) {
  int i = blockIdx.x * 256 + threadIdx.x;
  if (i >= total) return;
  float s = bias[i % Ncols];
  for (int z = 0; z < nz; z++) s += part[(size_t)z * total + i];
  if (OUTBF)
    ((ushort*)out)[i] = f2bf(s);
  else
    ((float*)out)[i] = s;
}

// ================= launch ====================================================================
extern "C" void kernel_launch(void* const* d_in, const int* in_sizes, int n_in, void* d_out,
                              int out_size, void* d_ws, size_t ws_size, hipStream_t stream) {
  (void)in_sizes; (void)n_in; (void)out_size; (void)ws_size;
  const float* points = (const float*)d_in[0];
  const float* feat_map = (const float*)d_in[1];
  const float* dw0 = (const float*)d_in[2];
  const float* db0 = (const float*)d_in[3];
  const float* aw0 = (const float*)d_in[4];
  const float* ab0 = (const float*)d_in[5];
  const float* lg0 = (const float*)d_in[6];
  const float* lb0 = (const float*)d_in[7];
  const float* dw1 = (const float*)d_in[8];
  const float* db1 = (const float*)d_in[9];
  const float* aw1 = (const float*)d_in[10];
  const float* ab1 = (const float*)d_in[11];
  const float* lg1 = (const float*)d_in[12];
  const float* lb1 = (const float*)d_in[13];
  const float* fw = (const float*)d_in[14];
  const float* fb = (const float*)d_in[15];
  const float* dmw = (const float*)d_in[16];
  const float* dmb = (const float*)d_in[17];
  float* out = (float*)d_out;

  char* wsb = (char*)d_ws;
  size_t off = 0;
  auto alloc = [&](size_t bytes) -> void* {
    void* p = wsb + off;
    off = (off + bytes + 255) & ~(size_t)255;
    return p;
  };
  float* fmT = (float*)alloc((size_t)1024 * 1024 * 4);
  ushort* Xb0 = (ushort*)alloc((size_t)B_ * N_ * LDP_ * 2);
  ushort* Gb = (ushort*)alloc((size_t)B_ * N_ * C_ * 2);
  ushort* Pb = (ushort*)alloc((size_t)B_ * S0_ * C_ * 2);
  ushort* Xb1 = (ushort*)alloc((size_t)B_ * S0_ * LDP_ * 2);
  ushort* fts2b = (ushort*)alloc((size_t)B_ * S1_ * C_ * 2);
  float* coords1 = (float*)alloc((size_t)B_ * S0_ * 2 * 4);
  ushort* awdb0 = (ushort*)alloc((size_t)C_ * LDP_ * 2);
  ushort* awab0 = (ushort*)alloc((size_t)C_ * LDP_ * 2);
  ushort* awdb1 = (ushort*)alloc((size_t)C_ * LDP_ * 2);
  ushort* awab1 = (ushort*)alloc((size_t)C_ * LDP_ * 2);
  ushort* dwT0 = (ushort*)alloc((size_t)LDP_ * LDP_ * 2);
  ushort* dwT1 = (ushort*)alloc((size_t)LDP_ * LDP_ * 2);
  ushort* Wcb0 = (ushort*)alloc((size_t)C_ * LDP_ * 2);
  ushort* Wcb1 = (ushort*)alloc((size_t)C_ * LDP_ * 2);
  float* dvp0 = (float*)alloc(1024 * 4);
  float* dvp1 = (float*)alloc(1024 * 4);
  int* rows0 = (int*)alloc(B_ * S0_ * 4);
  int* nn0 = (int*)alloc(B_ * S0_ * K_ * 4);
  int* rows1 = (int*)alloc(B_ * S1_ * 4);
  int* nn1 = (int*)alloc(B_ * S1_ * K_ * 4);
  float* hpart = (float*)alloc((size_t)32 * B_ * C_ * 4);
  ushort* hidb = (ushort*)alloc((size_t)B_ * C_ * 2);
  float* opart = (float*)alloc((size_t)4 * B_ * OUT_ * 4);

  // 1) weight prep + feat_map transpose
  k_prep<<<PREP_TOTAL, 256, 0, stream>>>(aw0, aw1, dw0, dw1, db0, ab0, db1, ab1, feat_map, awdb0,
                                         awab0, awdb1, awab1, dwT0, dwT1, dvp0, dvp1, fmT);
  // 2) FPS0 (prio 3, DS-free) || Wc combine GEMMs || bilinear sample
  k_wc_bil<<<32 + 144 + B_ * N_, 256, 0, stream>>>(awdb0, dwT0, Wcb0, awdb1, dwT1, Wcb1, points,
                                                   fmT, Xb0, rows0);
  // 3) stage 0: G0 big || P0 big || kNN0 (512-thread blocks; 1792 = 512+256+1024)
  k_stage0<<<1792, 512, 0, stream>>>(Xb0, Wcb0, Gb, rows0, awab0, dvp0, Pb, points, nn0);
  // 4) fused stage 0 (XCD-chunked swizzle)
  k_fused_stage<<<B_ * S0_, 256, 0, stream>>>(Gb, Pb, rows0, nn0, lg0, lb0, points, 2, Xb1, LDP_,
                                              coords1);
  // 5) stage 1: FPS1 (prio 3) || G1 big (512-thread blocks)
  k_gemm_fps1<<<32 + 256, 512, 0, stream>>>(Xb1, Wcb1, Gb, coords1, rows1);
  // 6) stage 1: P1 GEMM (nrb=16) || kNN1 (DS-free)
  k_gemm_knn<4><<<128 + (B_ * S1_) / 4, 256, 0, stream>>>(16, B_ * S1_, Xb1, LDP_, rows1, awab1,
                                                          dvp1, Pb, 128, S1_, S0_, coords1, 2,
                                                          rows1, nn1);
  // 7) fused stage 1 (XCD-chunked swizzle)
  k_fused_stage<<<B_ * S1_, 256, 0, stream>>>(Gb, Pb, rows1, nn1, lg1, lb1, nullptr, 0, fts2b, C_,
                                              nullptr);
  // 8) flat head (fused f32 W conversion), K-split 32 x 2048
  {
    dim3 g(8, 1, 32);
    k_flat<<<g, 256, 0, stream>>>(fts2b, fw, hpart);
  }
  // 9) reduce -> hid (bf16)
  k_reduce<1><<<(B_ * C_ + 255) / 256, 256, 0, stream>>>(B_ * C_, C_, 32, hpart, fb, hidb);
  // 10) dim head (fused f32 dmw conversion), z-split 4 x 256
  {
    dim3 g(28, 1, 4);
    k_dim<<<g, 256, 0, stream>>>(hidb, dmw, opart);
  }
  // 11) reduce -> out
  k_reduce<0><<<(B_ * OUT_ + 255) / 256, 256, 0, stream>>>(B_ * OUT_, OUT_, 4, opart, dmb, out);
}